// Round 7
// baseline (587.827 us; speedup 1.0000x reference)
//
#include <hip/hip_runtime.h>
#include <hip/hip_bf16.h>

// MinGRU fused: Y = scan of h = a*h + (1-a)*g along L, with
//   a = sigmoid(-(x@Wz^T+bz)),  g = g_fn(x@Wn^T+bn)
// B=4, L=4096, D=2048.
// GEMM: 256x256 tile, BK=64, 8-phase schedule, 2-tile-deep prefetch.

#define D_DIM 2048
#define B_DIM 4
#define L_DIM 4096
#define M_DIM (B_DIM * L_DIM)      // 16384 GEMM rows
#define KDIM  D_DIM                // GEMM K
#define NT    (KDIM / 64)          // 32 K-tiles
#define CHUNK 64
#define NCHUNK (L_DIM / CHUNK)     // 64

typedef __bf16 bf16x8 __attribute__((ext_vector_type(8)));
typedef float  f32x4  __attribute__((ext_vector_type(4)));

__device__ __forceinline__ unsigned short f2bf(float f) {
  unsigned int u = __float_as_uint(f);
  u += 0x7FFFu + ((u >> 16) & 1u);   // RNE
  return (unsigned short)(u >> 16);
}
__device__ __forceinline__ float bflo(unsigned int u) {
  return __uint_as_float(u << 16);
}
__device__ __forceinline__ float bfhi(unsigned int u) {
  return __uint_as_float(u & 0xFFFF0000u);
}

__device__ __forceinline__ void load_lds16(const void* g, void* l) {
  __builtin_amdgcn_global_load_lds(
      (const __attribute__((address_space(1))) void*)g,
      (__attribute__((address_space(3))) void*)l, 16, 0, 0);
}

// ---------------- cast x, Wz, Wn -> bf16 (xb[M][K], wb[NCOL][K]) ----------------
__global__ __launch_bounds__(256) void cast_inputs(
    const float* __restrict__ x, const float* __restrict__ Wz,
    const float* __restrict__ Wn,
    unsigned short* __restrict__ xb, unsigned short* __restrict__ wb) {
  const size_t MK4 = (size_t)M_DIM * KDIM / 4;   // 8388608 groups
  const size_t DD4 = (size_t)D_DIM * D_DIM / 4;  // 1048576 groups
  size_t i = (size_t)blockIdx.x * 256 + threadIdx.x;
  const float4* src; ushort4* dst; size_t off;
  if (i < MK4)            { src = (const float4*)x;  dst = (ushort4*)xb; off = i; }
  else if (i < MK4 + DD4) { src = (const float4*)Wz; dst = (ushort4*)wb; off = i - MK4; }
  else                    { src = (const float4*)Wn;
                            dst = (ushort4*)(wb + (size_t)D_DIM * D_DIM);
                            off = i - MK4 - DD4; }
  float4 v = src[off];
  ushort4 o;
  o.x = f2bf(v.x); o.y = f2bf(v.y); o.z = f2bf(v.z); o.w = f2bf(v.w);
  dst[off] = o;
}

// ---------------- GEMM: 256x256 8-phase, 2-tile-deep prefetch ----------------
// LDS per buf: regions [A0,A1,B0,B1] of [128 rows][64 cols] bf16 (16KB each).
// Region read map (workgroup-wide): A regions read at g1 AND g3; B regions at
// g1 AND g2. => earliest safe overwrite of buf[cur]: B at g3, A at g4.
// Tile U+2 is staged into buf[cur] WITHIN iter U: B0@g3; B1,A0,A1@g4.
// Steady-state ledger at U.g4 wait: outstanding = tile U+1 (8, issued iter U-1
// g3/g4) + tile U+2 (8, this iter) = 16 -> vmcnt(8) drains exactly tile U+1.
// Min issue->wait distance = 4 phases (vs 2 in the round-6 version).
// Swizzle: 16B-slot ^= (row&7) on global SOURCE + on ds_read (rule 21).
__global__ __launch_bounds__(512, 2) void gemm_fused(
    const unsigned short* __restrict__ xb, const unsigned short* __restrict__ wb,
    const float* __restrict__ bzv, const float* __restrict__ bnv,
    unsigned short* __restrict__ Ab, unsigned short* __restrict__ Gb) {
  __shared__ unsigned short lds[2][4][8192];   // [buf][A0,A1,B0,B1][128*64]
  const int t = threadIdx.x;
  const int lane = t & 63;
  const int wid = t >> 6;             // 0..7
  const int wm = wid >> 2, wn = wid & 3;
  const int laneRow = lane & 15, lg = lane >> 4;

  // XCD-aware swizzle: 1024 wgs % 8 == 0 -> simple bijective form
  const int bid = blockIdx.x;
  const int swz = (bid & 7) * 128 + (bid >> 3);
  const int mtile = swz >> 4;         // 0..63
  const int ntile = swz & 15;         // 0..15 (consecutive share A-panel)

  const unsigned short* aBase = xb + (size_t)mtile * 256 * KDIM;
  const unsigned short* bBase = wb + (size_t)ntile * 256 * KDIM;

  // staging constants: thread t covers LDS chunks t and t+512 of a region
  const int r0 = t >> 3;              // row 0..63 (second load: +64)
  const int sSwz = (t & 7) ^ (r0 & 7);  // pre-swizzled global slot

#define STAGE(buf, reg, srcB, halfRow, kt) do {                                   \
    const unsigned short* s_ = (srcB) + (size_t)((halfRow) + r0) * KDIM           \
                               + (kt) * 64 + sSwz * 8;                            \
    unsigned short* d_ = &lds[buf][reg][t * 8];                                   \
    load_lds16(s_, d_);                                                           \
    load_lds16(s_ + 64 * KDIM, d_ + 4096);                                        \
  } while (0)

  // swizzled read slot offsets (shorts): slot = (ksub*4+lg) ^ (laneRow&7)
  const int sA0 = ((0 + lg) ^ (laneRow & 7)) * 8;
  const int sA1 = ((4 + lg) ^ (laneRow & 7)) * 8;
  const int bRow0 = (wn & 1) * 64;

  f32x4 acc[8][4] = {};

  // prologue: stage tiles 0 and 1 fully (16 loads); wait tile0 landed
  STAGE(0, 2, bBase, 0, 0);  STAGE(0, 3, bBase, 128, 0);
  STAGE(0, 0, aBase, 0, 0);  STAGE(0, 1, aBase, 128, 0);
  STAGE(1, 2, bBase, 0, 1);  STAGE(1, 3, bBase, 128, 1);
  STAGE(1, 0, aBase, 0, 1);  STAGE(1, 1, aBase, 128, 1);
  asm volatile("s_waitcnt vmcnt(8)" ::: "memory");
  __builtin_amdgcn_sched_barrier(0);
  __builtin_amdgcn_s_barrier();

#define MFMA_QUAD(qm, qn)                                                         \
  _Pragma("unroll") for (int m = 0; m < 4; ++m)                                   \
  _Pragma("unroll") for (int n = 0; n < 2; ++n)                                   \
  _Pragma("unroll") for (int k = 0; k < 2; ++k)                                   \
    acc[(qm)*4 + m][(qn)*2 + n] = __builtin_amdgcn_mfma_f32_16x16x32_bf16(        \
        aF[m*2 + k], bF[((qn)*2 + n)*2 + k], acc[(qm)*4 + m][(qn)*2 + n], 0, 0, 0)

  for (int U = 0; U < NT; ++U) {
    const int cur = U & 1;
    const unsigned short* ldsA = lds[cur][wm];
    const unsigned short* ldsB = lds[cur][2 + (wn >> 1)];
    bf16x8 aF[8], bF[8];

    // ---- g1: read A-low + B-low; MFMA quad(0,0) ----
#pragma unroll
    for (int m = 0; m < 4; ++m) {
      aF[m*2+0] = *(const bf16x8*)&ldsA[(m*16 + laneRow) * 64 + sA0];
      aF[m*2+1] = *(const bf16x8*)&ldsA[(m*16 + laneRow) * 64 + sA1];
    }
#pragma unroll
    for (int n = 0; n < 2; ++n) {
      bF[n*2+0] = *(const bf16x8*)&ldsB[(bRow0 + n*16 + laneRow) * 64 + sA0];
      bF[n*2+1] = *(const bf16x8*)&ldsB[(bRow0 + n*16 + laneRow) * 64 + sA1];
    }
    __builtin_amdgcn_s_barrier();
    __builtin_amdgcn_s_setprio(1);
    MFMA_QUAD(0, 0);
    __builtin_amdgcn_s_setprio(0);
    __builtin_amdgcn_s_barrier();

    // ---- g2: read B-high; MFMA quad(0,1) ----
#pragma unroll
    for (int n = 0; n < 2; ++n) {
      bF[4 + n*2+0] = *(const bf16x8*)&ldsB[(bRow0 + 32 + n*16 + laneRow) * 64 + sA0];
      bF[4 + n*2+1] = *(const bf16x8*)&ldsB[(bRow0 + 32 + n*16 + laneRow) * 64 + sA1];
    }
    __builtin_amdgcn_s_barrier();
    __builtin_amdgcn_s_setprio(1);
    MFMA_QUAD(0, 1);
    __builtin_amdgcn_s_setprio(0);
    __builtin_amdgcn_s_barrier();

    // ---- g3: read A-high; stage B0(U+2)->cur (B[cur] reads done at g2) ----
#pragma unroll
    for (int m = 0; m < 4; ++m) {
      aF[m*2+0] = *(const bf16x8*)&ldsA[(64 + m*16 + laneRow) * 64 + sA0];
      aF[m*2+1] = *(const bf16x8*)&ldsA[(64 + m*16 + laneRow) * 64 + sA1];
    }
    if (U + 2 < NT) STAGE(cur, 2, bBase, 0, U + 2);
    __builtin_amdgcn_s_barrier();
    __builtin_amdgcn_s_setprio(1);
    MFMA_QUAD(1, 0);
    __builtin_amdgcn_s_setprio(0);
    __builtin_amdgcn_s_barrier();

    // ---- g4: stage B1,A0,A1(U+2)->cur (A[cur] reads done at g3); wait ----
    if (U + 2 < NT) {
      STAGE(cur, 3, bBase, 128, U + 2);
      STAGE(cur, 0, aBase, 0, U + 2);
      STAGE(cur, 1, aBase, 128, U + 2);
      asm volatile("s_waitcnt vmcnt(8)" ::: "memory");   // tile U+1 landed
      __builtin_amdgcn_sched_barrier(0);
    } else if (U + 1 < NT) {
      asm volatile("s_waitcnt vmcnt(0)" ::: "memory");   // last prefetch landed
      __builtin_amdgcn_sched_barrier(0);
    }
    __builtin_amdgcn_s_barrier();
    __builtin_amdgcn_s_setprio(1);
    MFMA_QUAD(1, 1);
    __builtin_amdgcn_s_setprio(0);
    __builtin_amdgcn_s_barrier();
  }

  // ---- epilogue: bias + transform + bf16 store ----
  const int gcB = ntile * 256 + wn * 64;
  const int grB = mtile * 256 + wm * 128;
  const bool isZ = (ntile < 8);                // block-uniform
  unsigned short* outP = isZ ? Ab : Gb;
  float bias[4];
#pragma unroll
  for (int ni = 0; ni < 4; ++ni) {
    const int gc = gcB + ni * 16 + laneRow;
    bias[ni] = isZ ? bzv[gc] : bnv[gc - D_DIM];
  }
#pragma unroll
  for (int mi = 0; mi < 8; ++mi) {
#pragma unroll
    for (int ni = 0; ni < 4; ++ni) {
      const int gc = gcB + ni * 16 + laneRow;
      const int dcol = isZ ? gc : gc - D_DIM;
#pragma unroll
      for (int j = 0; j < 4; ++j) {
        const float val = acc[mi][ni][j] + bias[ni];
        const int gr = grB + mi * 16 + (lg << 2) + j;
        const size_t off = (size_t)gr * D_DIM + dcol;
        if (isZ) outP[off] = f2bf(1.0f / (1.0f + __expf(val)));
        else     outP[off] = f2bf(val >= 0.0f ? val + 0.5f
                                              : 1.0f / (1.0f + __expf(-val)));
      }
    }
  }
#undef STAGE
#undef MFMA_QUAD
}

// ---------------- blocked scan over L (4 channels per thread) ----------------
// pass1: per (b,chunk,dquad) compute (A,V) with h_end = A*h_start + V
__global__ __launch_bounds__(256) void scan_pass1(
    const unsigned short* __restrict__ Ab, const unsigned short* __restrict__ Gb,
    float* __restrict__ SA, float* __restrict__ SV) {
  const int tid = blockIdx.x * 256 + threadIdx.x;   // B*NCHUNK*D/4 = 131072
  const int dq = tid & 511;                         // d = dq*4
  const int c = (tid >> 9) & (NCHUNK - 1);
  const int b = tid >> 15;
  const uint2* A2 = (const uint2*)Ab;   // row = 512 uint2
  const uint2* G2 = (const uint2*)Gb;
  size_t base = ((size_t)b * L_DIM + (size_t)c * CHUNK) * 512 + dq;
  float A0 = 1.0f, A1 = 1.0f, A2r = 1.0f, A3 = 1.0f;
  float V0 = 0.0f, V1 = 0.0f, V2 = 0.0f, V3 = 0.0f;
#pragma unroll 8
  for (int i = 0; i < CHUNK; ++i) {
    uint2 av = A2[base + (size_t)i * 512];
    uint2 gv = G2[base + (size_t)i * 512];
    float a0 = bflo(av.x), a1 = bfhi(av.x), a2 = bflo(av.y), a3 = bfhi(av.y);
    float g0 = bflo(gv.x), g1 = bfhi(gv.x), g2 = bflo(gv.y), g3 = bfhi(gv.y);
    V0 = a0 * V0 + (1.0f - a0) * g0;  A0 *= a0;
    V1 = a1 * V1 + (1.0f - a1) * g1;  A1 *= a1;
    V2 = a2 * V2 + (1.0f - a2) * g2;  A2r *= a2;
    V3 = a3 * V3 + (1.0f - a3) * g3;  A3 *= a3;
  }
  const size_t sidx = ((size_t)b * NCHUNK + c) * D_DIM + (size_t)dq * 4;
  *(float4*)&SA[sidx] = make_float4(A0, A1, A2r, A3);
  *(float4*)&SV[sidx] = make_float4(V0, V1, V2, V3);
}

// pass2: sequential over chunks, store per-chunk starting h
__global__ __launch_bounds__(256) void scan_pass2(
    const float* __restrict__ SA, const float* __restrict__ SV,
    float* __restrict__ H0) {
  const int tid = blockIdx.x * 256 + threadIdx.x;   // B*D = 8192
  const int d = tid & (D_DIM - 1);
  const int b = tid >> 11;
  float h = 0.5f;
  for (int c = 0; c < NCHUNK; ++c) {
    size_t idx = ((size_t)b * NCHUNK + c) * D_DIM + d;
    H0[idx] = h;
    h = SA[idx] * h + SV[idx];
  }
}

// pass3: recompute within chunk from correct h_start, write fp32 output
__global__ __launch_bounds__(256) void scan_pass3(
    const unsigned short* __restrict__ Ab, const unsigned short* __restrict__ Gb,
    const float* __restrict__ H0, float* __restrict__ out) {
  const int tid = blockIdx.x * 256 + threadIdx.x;   // 131072
  const int dq = tid & 511;
  const int c = (tid >> 9) & (NCHUNK - 1);
  const int b = tid >> 15;
  const uint2* A2 = (const uint2*)Ab;
  const uint2* G2 = (const uint2*)Gb;
  size_t base = ((size_t)b * L_DIM + (size_t)c * CHUNK) * 512 + dq;
  const size_t hidx = ((size_t)b * NCHUNK + c) * D_DIM + (size_t)dq * 4;
  float4 h4 = *(const float4*)&H0[hidx];
  float h0 = h4.x, h1 = h4.y, h2 = h4.z, h3 = h4.w;
  float4* out4 = (float4*)out;
#pragma unroll 8
  for (int i = 0; i < CHUNK; ++i) {
    uint2 av = A2[base + (size_t)i * 512];
    uint2 gv = G2[base + (size_t)i * 512];
    float a0 = bflo(av.x), a1 = bfhi(av.x), a2 = bflo(av.y), a3 = bfhi(av.y);
    float g0 = bflo(gv.x), g1 = bfhi(gv.x), g2 = bflo(gv.y), g3 = bfhi(gv.y);
    h0 = a0 * h0 + (1.0f - a0) * g0;
    h1 = a1 * h1 + (1.0f - a1) * g1;
    h2 = a2 * h2 + (1.0f - a2) * g2;
    h3 = a3 * h3 + (1.0f - a3) * g3;
    out4[base + (size_t)i * 512] = make_float4(h0, h1, h2, h3);
  }
}

extern "C" void kernel_launch(void* const* d_in, const int* in_sizes, int n_in,
                              void* d_out, int out_size, void* d_ws, size_t ws_size,
                              hipStream_t stream) {
  const float* x  = (const float*)d_in[0];
  const float* Wz = (const float*)d_in[1];
  const float* bz = (const float*)d_in[2];
  const float* Wn = (const float*)d_in[3];
  const float* bn = (const float*)d_in[4];
  float* out = (float*)d_out;

  char* ws = (char*)d_ws;
  // workspace layout (total ~224.4 MB)
  unsigned short* xb = (unsigned short*)(ws);                       // 67108864 B
  unsigned short* wb = (unsigned short*)(ws + 67108864);            // 16777216 B
  unsigned short* Ab = (unsigned short*)(ws + 83886080);            // 67108864 B
  unsigned short* Gb = (unsigned short*)(ws + 150994944);           // 67108864 B
  float* SA = (float*)(ws + 218103808);                             // 2097152 B
  float* SV = (float*)(ws + 220200960);                             // 2097152 B
  float* H0 = (float*)(ws + 222298112);                             // 2097152 B

  cast_inputs<<<40960, 256, 0, stream>>>(x, Wz, Wn, xb, wb);
  gemm_fused<<<1024, 512, 0, stream>>>(xb, wb, bz, bn, Ab, Gb);
  scan_pass1<<<512, 256, 0, stream>>>(Ab, Gb, SA, SV);
  scan_pass2<<<32, 256, 0, stream>>>(SA, SV, H0);
  scan_pass3<<<512, 256, 0, stream>>>(Ab, Gb, H0, out);
}